// Round 1
// baseline (2861.116 us; speedup 1.0000x reference)
//
#include <hip/hip_runtime.h>
#include <hip/hip_bf16.h>

// ---------------- problem constants ----------------
// x: [B=8, N1=4, S=64, L=8192], PATCH=128 -> Lp=64, P=128, F=256, Lout=62
// out: [8,4,64,62,1] fp32

// ws float-word offsets
constexpr int WOFF_CNT   = 0;     // 16 uints: [0..7]=cnt_thr[b], [8..15]=cnt_pos[b]
constexpr int WOFF_STRAT = 16;    // 8 ints
constexpr int WOFF_CONST = 32;    // 1 float
constexpr int WOFF_VF    = 64;    // 256 floats
constexpr int WOFF_VB    = 320;   // 256 floats
constexpr int WOFF_CWT   = 1024;  // 2 * 768*256 floats (fwd then bwd), layout [kk=k*256+i][o]
constexpr int CWT_SZ     = 768 * 256;
constexpr size_t WOFF_NORM = (size_t)WOFF_CWT + 2 * (size_t)CWT_SZ;  // 8*64*1024 floats

__device__ __forceinline__ float silu_f(float v) {
    return v / (1.0f + __expf(-v));
}

// ---------------- decide stage ----------------
// grid 512 (= b*64+s), 256 threads: normalize each correlation row into ws
__global__ __launch_bounds__(256) void norm_kernel(const float* __restrict__ c,
                                                   float* __restrict__ wsf) {
    const int bs = blockIdx.x;
    const int tid = threadIdx.x;
    unsigned int* cnts = (unsigned int*)wsf + WOFF_CNT;
    if (bs == 0 && tid < 16) cnts[tid] = 0u;

    const float* row = c + (size_t)bs * 1024;
    float4 v = ((const float4*)row)[tid];
    float sum = v.x + v.y + v.z + v.w;
    float sq  = v.x*v.x + v.y*v.y + v.z*v.z + v.w*v.w;
    #pragma unroll
    for (int off = 32; off > 0; off >>= 1) {
        sum += __shfl_down(sum, off);
        sq  += __shfl_down(sq, off);
    }
    __shared__ float ls[8];
    __shared__ float stats[2];
    const int w = tid >> 6;
    if ((tid & 63) == 0) { ls[w] = sum; ls[4 + w] = sq; }
    __syncthreads();
    if (tid == 0) {
        float S = ls[0] + ls[1] + ls[2] + ls[3];
        float Q = ls[4] + ls[5] + ls[6] + ls[7];
        float mean = S * (1.0f / 1024.0f);
        float var  = (Q - 1024.0f * mean * mean) * (1.0f / 1023.0f);  // ddof=1
        stats[0] = mean;
        stats[1] = 1.0f / sqrtf(var);
    }
    __syncthreads();
    const float mean = stats[0], inv = stats[1];
    float4 o;
    o.x = (v.x - mean) * inv; o.y = (v.y - mean) * inv;
    o.z = (v.z - mean) * inv; o.w = (v.w - mean) * inv;
    ((float4*)(wsf + WOFF_NORM + (size_t)bs * 1024))[tid] = o;
}

// grid 512 (= b*64+s): corr row s vs all t, count corr>0.6 and corr>0 (t!=s)
__global__ __launch_bounds__(256) void rowcount_kernel(float* __restrict__ wsf) {
    const int bs = blockIdx.x;
    const int b = bs >> 6, s = bs & 63;
    const int tid = threadIdx.x;
    unsigned int* cnts = (unsigned int*)wsf + WOFF_CNT;
    const float* nb = wsf + WOFF_NORM + (size_t)b * 65536;

    __shared__ __align__(16) float rowv[1024];
    *(float4*)&rowv[tid * 4] = *(const float4*)&nb[s * 1024 + tid * 4];
    __syncthreads();

    const int t = tid >> 2, part = tid & 3;
    const float4* src  = (const float4*)(nb + t * 1024 + part * 256);
    const float4* mine = (const float4*)(rowv + part * 256);
    float acc = 0.0f;
    #pragma unroll 8
    for (int i = 0; i < 64; ++i) {
        float4 a = mine[i];
        float4 bb = src[i];
        acc += a.x * bb.x + a.y * bb.y + a.z * bb.z + a.w * bb.w;
    }
    acc += __shfl_down(acc, 2);
    acc += __shfl_down(acc, 1);
    const float corrv = acc * (1.0f / 1024.0f);
    const bool valid = (part == 0) && (t != s);
    unsigned long long mthr = __ballot(valid && (corrv > 0.6f));
    unsigned long long mpos = __ballot(valid && (corrv > 0.0f));
    if ((tid & 63) == 0) {
        atomicAdd(&cnts[b],     (unsigned int)__popcll(mthr));
        atomicAdd(&cnts[8 + b], (unsigned int)__popcll(mpos));
    }
}

// 1 block: strategy, v = W2@Wr, const term, Cw transpose into [kk][o]
__global__ __launch_bounds__(256) void finalize_kernel(
    const float* __restrict__ W2f, const float* __restrict__ b2f,
    const float* __restrict__ W2b, const float* __restrict__ b2b,
    const float* __restrict__ Wr,  const float* __restrict__ br,
    const float* __restrict__ Cwf, const float* __restrict__ Cwb,
    float* __restrict__ wsf) {
    const int tid = threadIdx.x;
    const unsigned int* cnts = (const unsigned int*)wsf + WOFF_CNT;
    int* strat = (int*)wsf + WOFF_STRAT;

    float vf = 0.0f, vb = 0.0f;
    for (int g = 0; g < 256; ++g) {
        float wr = Wr[g];
        vf = fmaf(W2f[tid * 256 + g], wr, vf);
        vb = fmaf(W2b[tid * 256 + g], wr, vb);
    }
    wsf[WOFF_VF + tid] = vf;
    wsf[WOFF_VB + tid] = vb;

    if (tid == 0) {
        float cc = 0.0f;
        for (int g = 0; g < 256; ++g) cc += (b2f[g] + b2b[g]) * Wr[g];
        wsf[WOFF_CONST] = cc + br[0];
        for (int bb = 0; bb < 8; ++bb) {
            unsigned int ct = cnts[bb], cp = cnts[8 + bb];
            unsigned int denom = cp < 1u ? 1u : cp;
            float ratio = (cp > 0u) ? ((float)ct / (float)denom) : 0.0f;
            strat[bb] = (ratio >= 0.4f) ? 1 : 0;
        }
    }

    float* cwtF = wsf + WOFF_CWT;
    float* cwtB = cwtF + CWT_SZ;
    for (int e = tid; e < CWT_SZ; e += 256) {
        int o = e & 255;
        int r = e >> 8;       // kk = k*256 + i
        int i = r & 255;
        int k = r >> 8;
        cwtF[e] = Cwf[(o * 256 + i) * 3 + k];
        cwtB[e] = Cwb[(o * 256 + i) * 3 + k];
    }
}

// ---------------- fused main ----------------
// one block per (b,n,s); both directions inside; out = sum_f silu(conv)*v[f] + const
__global__ __launch_bounds__(256, 3) void fused_main(
    const float* __restrict__ x,
    const float* __restrict__ W1f, const float* __restrict__ b1f, const float* __restrict__ Cbf,
    const float* __restrict__ W1b, const float* __restrict__ b1b, const float* __restrict__ Cbb,
    const float* __restrict__ wsf,
    float* __restrict__ out) {
    __shared__ __align__(16) float tok_lds[32 * 128];          // 16 KB, half-tile of tok
    __shared__ __align__(16) __hip_bfloat16 h_lds[64 * 256];   // 32 KB, post-silu h
    __shared__ float red[64];

    const int tid = threadIdx.x;
    const int m = blockIdx.x;
    const int b = m >> 8;
    const int n = (m >> 6) & 3;
    const int s = m & 63;
    const int f = tid;

    const int strat = ((const int*)wsf)[WOFF_STRAT + b];
    const float constv = wsf[WOFF_CONST];

    if (tid < 64) red[tid] = 0.0f;

    for (int dir = 0; dir < 2; ++dir) {
        const int sg = dir ? (63 - s) : s;   // bwd: flip along S
        const float* W1 = dir ? W1b : W1f;
        const float bb1 = (dir ? b1b : b1f)[f];

        // phase 1: h = silu(tok @ W1 + b1), two 32-row chunks
        for (int ch = 0; ch < 2; ++ch) {
            __syncthreads();  // protect tok_lds / h_lds vs previous phase
            #pragma unroll
            for (int q = 0; q < 4; ++q) {
                int lin = q * 256 + tid;   // float4 index in [0,1024)
                int row = lin >> 5;        // 0..31
                int c4  = lin & 31;
                int lp = ch * 32 + row;
                int r1 = strat ? lp : sg;  // row in [S] position of x
                int r2 = strat ? sg : lp;  // patch index
                const float* src = x + (((size_t)(b * 4 + n) * 64 + r1) * 8192
                                        + (size_t)r2 * 128 + c4 * 4);
                *(float4*)&tok_lds[row * 128 + c4 * 4] = *(const float4*)src;
            }
            __syncthreads();
            float acc2[32];
            #pragma unroll
            for (int i = 0; i < 32; ++i) acc2[i] = bb1;
            for (int p4 = 0; p4 < 128; p4 += 4) {
                float w0 = W1[(p4 + 0) * 256 + f];
                float w1 = W1[(p4 + 1) * 256 + f];
                float w2 = W1[(p4 + 2) * 256 + f];
                float w3 = W1[(p4 + 3) * 256 + f];
                #pragma unroll
                for (int i = 0; i < 32; ++i) {
                    float4 a = *(const float4*)&tok_lds[i * 128 + p4];
                    float t = acc2[i];
                    t = fmaf(a.x, w0, t);
                    t = fmaf(a.y, w1, t);
                    t = fmaf(a.z, w2, t);
                    t = fmaf(a.w, w3, t);
                    acc2[i] = t;
                }
            }
            #pragma unroll
            for (int i = 0; i < 32; ++i) {
                h_lds[(ch * 32 + i) * 256 + f] = __float2bfloat16(silu_f(acc2[i]));
            }
        }
        __syncthreads();

        // phase 2: conv (K=768 over 3 contiguous h-rows) + silu + dot v
        const float* cwt = wsf + WOFF_CWT + (dir ? CWT_SZ : 0);
        const float vf = wsf[(dir ? WOFF_VB : WOFF_VF) + f];
        const float cb = (dir ? Cbb : Cbf)[f];
        float acc[62];
        #pragma unroll
        for (int l = 0; l < 62; ++l) acc[l] = 0.0f;
        const unsigned short* hl = (const unsigned short*)h_lds;
        for (int kk = 0; kk < 768; kk += 8) {
            float w[8];
            #pragma unroll
            for (int j = 0; j < 8; ++j) w[j] = cwt[(kk + j) * 256 + f];
            #pragma unroll
            for (int l = 0; l < 62; ++l) {
                uint4 raw = *(const uint4*)(hl + l * 256 + kk);  // 8 bf16, broadcast read
                float t = acc[l];
                t = fmaf(__uint_as_float(raw.x << 16),          w[0], t);
                t = fmaf(__uint_as_float(raw.x & 0xffff0000u),  w[1], t);
                t = fmaf(__uint_as_float(raw.y << 16),          w[2], t);
                t = fmaf(__uint_as_float(raw.y & 0xffff0000u),  w[3], t);
                t = fmaf(__uint_as_float(raw.z << 16),          w[4], t);
                t = fmaf(__uint_as_float(raw.z & 0xffff0000u),  w[5], t);
                t = fmaf(__uint_as_float(raw.w << 16),          w[6], t);
                t = fmaf(__uint_as_float(raw.w & 0xffff0000u),  w[7], t);
                acc[l] = t;
            }
        }
        #pragma unroll
        for (int l = 0; l < 62; ++l) {
            float ctr = silu_f(acc[l] + cb) * vf;
            #pragma unroll
            for (int off = 32; off > 0; off >>= 1) ctr += __shfl_down(ctr, off);
            if ((tid & 63) == 0) atomicAdd(&red[l], ctr);
        }
    }
    __syncthreads();
    if (tid < 62) {
        out[((size_t)(b * 4 + n) * 64 + s) * 62 + tid] = red[tid] + constv;
    }
}

extern "C" void kernel_launch(void* const* d_in, const int* in_sizes, int n_in,
                              void* d_out, int out_size, void* d_ws, size_t ws_size,
                              hipStream_t stream) {
    (void)in_sizes; (void)n_in; (void)out_size; (void)ws_size;
    const float* x    = (const float*)d_in[0];
    const float* corr = (const float*)d_in[1];
    const float* W1f  = (const float*)d_in[2];
    const float* b1f  = (const float*)d_in[3];
    const float* Cwf  = (const float*)d_in[4];
    const float* Cbf  = (const float*)d_in[5];
    const float* W2f  = (const float*)d_in[6];
    const float* b2f  = (const float*)d_in[7];
    const float* W1b  = (const float*)d_in[8];
    const float* b1b  = (const float*)d_in[9];
    const float* Cwb  = (const float*)d_in[10];
    const float* Cbb  = (const float*)d_in[11];
    const float* W2b  = (const float*)d_in[12];
    const float* b2b  = (const float*)d_in[13];
    const float* Wr   = (const float*)d_in[14];
    const float* br   = (const float*)d_in[15];
    float* out = (float*)d_out;
    float* wsf = (float*)d_ws;

    norm_kernel<<<512, 256, 0, stream>>>(corr, wsf);
    rowcount_kernel<<<512, 256, 0, stream>>>(wsf);
    finalize_kernel<<<1, 256, 0, stream>>>(W2f, b2f, W2b, b2b, Wr, br, Cwf, Cwb, wsf);
    fused_main<<<2048, 256, 0, stream>>>(x, W1f, b1f, Cbf, W1b, b1b, Cbb, wsf, out);
}

// Round 2
// 863.668 us; speedup vs baseline: 3.3127x; 3.3127x over previous
//
#include <hip/hip_runtime.h>
#include <hip/hip_bf16.h>

// ---------------- problem constants ----------------
// x: [B=8, N1=4, S=64, L=8192], PATCH=128 -> Lp=64, P=128, F=256, Lout=62
// out: [8,4,64,62,1] fp32

typedef _Float16 fp16_t;
typedef _Float16 fp16x8 __attribute__((ext_vector_type(8)));
typedef float f32x4 __attribute__((ext_vector_type(4)));

// ws float-word offsets
constexpr int WOFF_CNT   = 0;     // 16 uints
constexpr int WOFF_STRAT = 16;    // 8 ints
constexpr int WOFF_CONST = 32;    // 1 float
constexpr int WOFF_VF    = 64;    // 256 floats
constexpr int WOFF_VB    = 320;   // 256 floats
constexpr int WOFF_NORM  = 1024;                // 8*64*1024 floats
constexpr int WOFF_W1T   = WOFF_NORM + 524288;  // f16 [2][4][256][32]   (as float words: 16384)
constexpr int WOFF_CWT   = WOFF_W1T + 32768;    // f16 [2][24][256][32]  (float words: 196608)

__device__ __forceinline__ float silu_f(float v) {
    return v / (1.0f + __expf(-v));
}

// ---------------- decide stage (unchanged, verified R1) ----------------
__global__ __launch_bounds__(256) void norm_kernel(const float* __restrict__ c,
                                                   float* __restrict__ wsf) {
    const int bs = blockIdx.x;
    const int tid = threadIdx.x;
    unsigned int* cnts = (unsigned int*)wsf + WOFF_CNT;
    if (bs == 0 && tid < 16) cnts[tid] = 0u;

    const float* row = c + (size_t)bs * 1024;
    float4 v = ((const float4*)row)[tid];
    float sum = v.x + v.y + v.z + v.w;
    float sq  = v.x*v.x + v.y*v.y + v.z*v.z + v.w*v.w;
    #pragma unroll
    for (int off = 32; off > 0; off >>= 1) {
        sum += __shfl_down(sum, off);
        sq  += __shfl_down(sq, off);
    }
    __shared__ float ls[8];
    __shared__ float stats[2];
    const int w = tid >> 6;
    if ((tid & 63) == 0) { ls[w] = sum; ls[4 + w] = sq; }
    __syncthreads();
    if (tid == 0) {
        float S = ls[0] + ls[1] + ls[2] + ls[3];
        float Q = ls[4] + ls[5] + ls[6] + ls[7];
        float mean = S * (1.0f / 1024.0f);
        float var  = (Q - 1024.0f * mean * mean) * (1.0f / 1023.0f);
        stats[0] = mean;
        stats[1] = 1.0f / sqrtf(var);
    }
    __syncthreads();
    const float mean = stats[0], inv = stats[1];
    float4 o;
    o.x = (v.x - mean) * inv; o.y = (v.y - mean) * inv;
    o.z = (v.z - mean) * inv; o.w = (v.w - mean) * inv;
    ((float4*)(wsf + WOFF_NORM + (size_t)bs * 1024))[tid] = o;
}

__global__ __launch_bounds__(256) void rowcount_kernel(float* __restrict__ wsf) {
    const int bs = blockIdx.x;
    const int b = bs >> 6, s = bs & 63;
    const int tid = threadIdx.x;
    unsigned int* cnts = (unsigned int*)wsf + WOFF_CNT;
    const float* nb = wsf + WOFF_NORM + (size_t)b * 65536;

    __shared__ __align__(16) float rowv[1024];
    *(float4*)&rowv[tid * 4] = *(const float4*)&nb[s * 1024 + tid * 4];
    __syncthreads();

    const int t = tid >> 2, part = tid & 3;
    const float4* src  = (const float4*)(nb + t * 1024 + part * 256);
    const float4* mine = (const float4*)(rowv + part * 256);
    float acc = 0.0f;
    #pragma unroll 8
    for (int i = 0; i < 64; ++i) {
        float4 a = mine[i];
        float4 bb = src[i];
        acc += a.x * bb.x + a.y * bb.y + a.z * bb.z + a.w * bb.w;
    }
    acc += __shfl_down(acc, 2);
    acc += __shfl_down(acc, 1);
    const float corrv = acc * (1.0f / 1024.0f);
    const bool valid = (part == 0) && (t != s);
    unsigned long long mthr = __ballot(valid && (corrv > 0.6f));
    unsigned long long mpos = __ballot(valid && (corrv > 0.0f));
    if ((tid & 63) == 0) {
        atomicAdd(&cnts[b],     (unsigned int)__popcll(mthr));
        atomicAdd(&cnts[8 + b], (unsigned int)__popcll(mpos));
    }
}

// 1 block: strategy, v = W2@Wr, const term, and f16 k-slice-tiled weight packs
__global__ __launch_bounds__(256) void finalize_kernel(
    const float* __restrict__ W2f, const float* __restrict__ b2f,
    const float* __restrict__ W2b, const float* __restrict__ b2b,
    const float* __restrict__ Wr,  const float* __restrict__ br,
    const float* __restrict__ W1f, const float* __restrict__ W1b,
    const float* __restrict__ Cwf, const float* __restrict__ Cwb,
    float* __restrict__ wsf) {
    const int tid = threadIdx.x;
    const unsigned int* cnts = (const unsigned int*)wsf + WOFF_CNT;
    int* strat = (int*)wsf + WOFF_STRAT;

    float vf = 0.0f, vb = 0.0f;
    for (int g = 0; g < 256; ++g) {
        float wr = Wr[g];
        vf = fmaf(W2f[tid * 256 + g], wr, vf);
        vb = fmaf(W2b[tid * 256 + g], wr, vb);
    }
    wsf[WOFF_VF + tid] = vf;
    wsf[WOFF_VB + tid] = vb;

    if (tid == 0) {
        float cc = 0.0f;
        for (int g = 0; g < 256; ++g) cc += (b2f[g] + b2b[g]) * Wr[g];
        wsf[WOFF_CONST] = cc + br[0];
        for (int bb = 0; bb < 8; ++bb) {
            unsigned int ct = cnts[bb], cp = cnts[8 + bb];
            unsigned int denom = cp < 1u ? 1u : cp;
            float ratio = (cp > 0u) ? ((float)ct / (float)denom) : 0.0f;
            strat[bb] = (ratio >= 0.4f) ? 1 : 0;
        }
    }

    // pack weights as f16, k-slice tiled: slice ks is contiguous [256 o][32 kk]
    for (int d = 0; d < 2; ++d) {
        const float* W1 = d ? W1b : W1f;
        fp16_t* w1t = (fp16_t*)(wsf + WOFF_W1T) + d * 32768;
        for (int kkg = 0; kkg < 128; ++kkg) {           // kkg = p
            int ks = kkg >> 5, kk = kkg & 31;
            w1t[(ks * 256 + tid) * 32 + kk] = (fp16_t)W1[kkg * 256 + tid];
        }
        const float* Cw = d ? Cwb : Cwf;
        fp16_t* cwt = (fp16_t*)(wsf + WOFF_CWT) + d * 196608;
        for (int kkg = 0; kkg < 768; ++kkg) {           // kkg = k*256 + i
            int ks = kkg >> 5, kk = kkg & 31;
            cwt[(ks * 256 + tid) * 32 + kk] =
                (fp16_t)Cw[(tid * 256 + (kkg & 255)) * 3 + (kkg >> 8)];
        }
    }
}

// ---------------- fused main (MFMA) ----------------
// 1 block per (b,n,s), 4 waves. Wave w owns output cols [64w, 64w+64).
// GEMM1: h[64][256] = silu(tok@W1+b1), A-frags straight from global x.
// conv:  A[l][kk] = h_flat[l*256+kk] (row stride 256, overlapping) vs Cwt.
__global__ __launch_bounds__(256, 3) void fused_main(
    const float* __restrict__ x,
    const float* __restrict__ b1f, const float* __restrict__ Cbf,
    const float* __restrict__ b1b, const float* __restrict__ Cbb,
    const float* __restrict__ wsf,
    float* __restrict__ out) {
    __shared__ __align__(16) char hbytes[66 * 512];  // h [66][256] f16, rows XOR-swizzled
    __shared__ __align__(16) char bsl[256 * 80];     // weight k-slice, 80B-padded rows
    __shared__ float red[64];

    const int tid  = threadIdx.x;
    const int w    = tid >> 6;
    const int lane = tid & 63;
    const int l15  = lane & 15;
    const int l4   = lane >> 4;   // 0..3

    const int mb = blockIdx.x;
    const int b  = mb >> 8;
    const int n  = (mb >> 6) & 3;
    const int s  = mb & 63;
    const size_t bn = (size_t)(b * 4 + n);

    const int strat = ((const int*)wsf)[WOFF_STRAT + b];

    if (tid < 64) red[tid] = 0.0f;
    ((unsigned int*)(hbytes + 64 * 512))[tid] = 0u;  // zero pad rows 64,65

    for (int dir = 0; dir < 2; ++dir) {
        const int sg = dir ? (63 - s) : s;
        const float* b1 = dir ? b1b : b1f;
        const float* cb = dir ? Cbb : Cbf;
        const char* w1sl = (const char*)(wsf + WOFF_W1T) + dir * 65536;
        const char* cwsl = (const char*)(wsf + WOFF_CWT) + dir * 393216;

        float b1v[4], cbv[4], vv[4];
        #pragma unroll
        for (int t = 0; t < 4; ++t) {
            int col = w * 64 + t * 16 + l15;
            b1v[t] = b1[col];
            cbv[t] = cb[col];
            vv[t]  = wsf[(dir ? WOFF_VB : WOFF_VF) + col];
        }

        // ---------- GEMM1: K=128, 4 k-slices ----------
        f32x4 acc1[4][4];
        #pragma unroll
        for (int i = 0; i < 4; ++i)
            #pragma unroll
            for (int j = 0; j < 4; ++j)
                acc1[i][j] = (f32x4){0.f, 0.f, 0.f, 0.f};

        for (int ks = 0; ks < 4; ++ks) {
            const uint4* src = (const uint4*)(w1sl + ks * 16384 + tid * 64);
            uint4 r0 = src[0], r1 = src[1], r2 = src[2], r3 = src[3];
            __syncthreads();   // bsl free (prev compute done)
            uint4* dst = (uint4*)(bsl + tid * 80);
            dst[0] = r0; dst[1] = r1; dst[2] = r2; dst[3] = r3;
            // A-frags from global x while the slice lands
            fp16x8 af[4];
            #pragma unroll
            for (int mt = 0; mt < 4; ++mt) {
                int lp  = mt * 16 + l15;
                int r1i = strat ? lp : sg;
                int r2i = strat ? sg : lp;
                const float* xp = x + ((bn * 64 + r1i) * 8192
                                       + (size_t)r2i * 128 + ks * 32 + l4 * 8);
                float4 p0 = *(const float4*)xp;
                float4 p1 = *(const float4*)(xp + 4);
                fp16x8 a;
                a[0] = (fp16_t)p0.x; a[1] = (fp16_t)p0.y;
                a[2] = (fp16_t)p0.z; a[3] = (fp16_t)p0.w;
                a[4] = (fp16_t)p1.x; a[5] = (fp16_t)p1.y;
                a[6] = (fp16_t)p1.z; a[7] = (fp16_t)p1.w;
                af[mt] = a;
            }
            __syncthreads();   // slice ready
            #pragma unroll
            for (int t = 0; t < 4; ++t) {
                int o = w * 64 + t * 16 + l15;
                fp16x8 bf = *(const fp16x8*)(bsl + o * 80 + l4 * 16);
                #pragma unroll
                for (int mt = 0; mt < 4; ++mt)
                    acc1[mt][t] = __builtin_amdgcn_mfma_f32_16x16x32_f16(
                        af[mt], bf, acc1[mt][t], 0, 0, 0);
            }
        }

        // h = silu(acc + b1) -> LDS f16, XOR-swizzled rows
        #pragma unroll
        for (int mt = 0; mt < 4; ++mt) {
            #pragma unroll
            for (int t = 0; t < 4; ++t) {
                int col = w * 64 + t * 16 + l15;
                #pragma unroll
                for (int q = 0; q < 4; ++q) {
                    int row = mt * 16 + l4 * 4 + q;
                    float hv = silu_f(acc1[mt][t][q] + b1v[t]);
                    int off = (row * 512 + col * 2) ^ ((row & 7) << 4);
                    *(fp16_t*)(hbytes + off) = (fp16_t)hv;
                }
            }
        }

        // ---------- conv GEMM: K=768, 24 k-slices ----------
        f32x4 acc2[4][4];
        #pragma unroll
        for (int i = 0; i < 4; ++i)
            #pragma unroll
            for (int j = 0; j < 4; ++j)
                acc2[i][j] = (f32x4){0.f, 0.f, 0.f, 0.f};

        for (int ks = 0; ks < 24; ++ks) {
            const uint4* src = (const uint4*)(cwsl + ks * 16384 + tid * 64);
            uint4 r0 = src[0], r1 = src[1], r2 = src[2], r3 = src[3];
            __syncthreads();   // prev compute done; also h writes done (first iter)
            uint4* dst = (uint4*)(bsl + tid * 80);
            dst[0] = r0; dst[1] = r1; dst[2] = r2; dst[3] = r3;
            fp16x8 af[4];
            #pragma unroll
            for (int mt = 0; mt < 4; ++mt) {
                int l  = mt * 16 + l15;
                int fb = l * 512 + ks * 64 + l4 * 16;
                int ad = fb ^ (((fb >> 9) & 7) << 4);
                af[mt] = *(const fp16x8*)(hbytes + ad);
            }
            __syncthreads();   // slice ready
            #pragma unroll
            for (int t = 0; t < 4; ++t) {
                int o = w * 64 + t * 16 + l15;
                fp16x8 bf = *(const fp16x8*)(bsl + o * 80 + l4 * 16);
                #pragma unroll
                for (int mt = 0; mt < 4; ++mt)
                    acc2[mt][t] = __builtin_amdgcn_mfma_f32_16x16x32_f16(
                        af[mt], bf, acc2[mt][t], 0, 0, 0);
            }
        }

        // epilogue: silu(conv + cb) * v, col-sum -> red[row]
        #pragma unroll
        for (int mt = 0; mt < 4; ++mt) {
            #pragma unroll
            for (int q = 0; q < 4; ++q) {
                float v0 = 0.f;
                #pragma unroll
                for (int t = 0; t < 4; ++t)
                    v0 += silu_f(acc2[mt][t][q] + cbv[t]) * vv[t];
                v0 += __shfl_xor(v0, 1);
                v0 += __shfl_xor(v0, 2);
                v0 += __shfl_xor(v0, 4);
                v0 += __shfl_xor(v0, 8);
                if (l15 == 0) {
                    int row = mt * 16 + l4 * 4 + q;
                    atomicAdd(&red[row], v0);
                }
            }
        }
    }

    __syncthreads();
    if (tid < 62)
        out[(bn * 64 + s) * 62 + tid] = red[tid] + wsf[WOFF_CONST];
}

extern "C" void kernel_launch(void* const* d_in, const int* in_sizes, int n_in,
                              void* d_out, int out_size, void* d_ws, size_t ws_size,
                              hipStream_t stream) {
    (void)in_sizes; (void)n_in; (void)out_size; (void)ws_size;
    const float* x    = (const float*)d_in[0];
    const float* corr = (const float*)d_in[1];
    const float* W1f  = (const float*)d_in[2];
    const float* b1f  = (const float*)d_in[3];
    const float* Cwf  = (const float*)d_in[4];
    const float* Cbf  = (const float*)d_in[5];
    const float* W2f  = (const float*)d_in[6];
    const float* b2f  = (const float*)d_in[7];
    const float* W1b  = (const float*)d_in[8];
    const float* b1b  = (const float*)d_in[9];
    const float* Cwb  = (const float*)d_in[10];
    const float* Cbb  = (const float*)d_in[11];
    const float* W2b  = (const float*)d_in[12];
    const float* b2b  = (const float*)d_in[13];
    const float* Wr   = (const float*)d_in[14];
    const float* br   = (const float*)d_in[15];
    float* out = (float*)d_out;
    float* wsf = (float*)d_ws;

    norm_kernel<<<512, 256, 0, stream>>>(corr, wsf);
    rowcount_kernel<<<512, 256, 0, stream>>>(wsf);
    finalize_kernel<<<1, 256, 0, stream>>>(W2f, b2f, W2b, b2b, Wr, br,
                                           W1f, W1b, Cwf, Cwb, wsf);
    fused_main<<<2048, 256, 0, stream>>>(x, b1f, Cbf, b1b, Cbb, wsf, out);
}

// Round 3
// 471.475 us; speedup vs baseline: 6.0684x; 1.8318x over previous
//
#include <hip/hip_runtime.h>
#include <hip/hip_bf16.h>

// ---------------- problem constants ----------------
// x: [B=8, N1=4, S=64, L=8192], PATCH=128 -> Lp=64, P=128, F=256, Lout=62
// out: [8,4,64,62,1] fp32

typedef _Float16 fp16_t;
typedef _Float16 fp16x8 __attribute__((ext_vector_type(8)));
typedef float f32x4 __attribute__((ext_vector_type(4)));

// ws float-word offsets
constexpr int WOFF_CNT   = 0;     // 16 uints
constexpr int WOFF_STRAT = 16;    // 8 ints
constexpr int WOFF_CONST = 32;    // 1 float
constexpr int WOFF_VF    = 64;    // 256 floats
constexpr int WOFF_VB    = 320;   // 256 floats
constexpr int WOFF_NORM  = 1024;                // 8*64*1024 floats
constexpr int WOFF_W1T   = WOFF_NORM + 524288;  // f16 [2][4][256][32]
constexpr int WOFF_CWT   = WOFF_W1T + 32768;    // f16 [2][24][256][32]

__device__ __forceinline__ float silu_f(float v) {
    return v / (1.0f + __expf(-v));
}

// ---------------- decide stage (unchanged, verified) ----------------
__global__ __launch_bounds__(256) void norm_kernel(const float* __restrict__ c,
                                                   float* __restrict__ wsf) {
    const int bs = blockIdx.x;
    const int tid = threadIdx.x;
    unsigned int* cnts = (unsigned int*)wsf + WOFF_CNT;
    if (bs == 0 && tid < 16) cnts[tid] = 0u;

    const float* row = c + (size_t)bs * 1024;
    float4 v = ((const float4*)row)[tid];
    float sum = v.x + v.y + v.z + v.w;
    float sq  = v.x*v.x + v.y*v.y + v.z*v.z + v.w*v.w;
    #pragma unroll
    for (int off = 32; off > 0; off >>= 1) {
        sum += __shfl_down(sum, off);
        sq  += __shfl_down(sq, off);
    }
    __shared__ float ls[8];
    __shared__ float stats[2];
    const int w = tid >> 6;
    if ((tid & 63) == 0) { ls[w] = sum; ls[4 + w] = sq; }
    __syncthreads();
    if (tid == 0) {
        float S = ls[0] + ls[1] + ls[2] + ls[3];
        float Q = ls[4] + ls[5] + ls[6] + ls[7];
        float mean = S * (1.0f / 1024.0f);
        float var  = (Q - 1024.0f * mean * mean) * (1.0f / 1023.0f);
        stats[0] = mean;
        stats[1] = 1.0f / sqrtf(var);
    }
    __syncthreads();
    const float mean = stats[0], inv = stats[1];
    float4 o;
    o.x = (v.x - mean) * inv; o.y = (v.y - mean) * inv;
    o.z = (v.z - mean) * inv; o.w = (v.w - mean) * inv;
    ((float4*)(wsf + WOFF_NORM + (size_t)bs * 1024))[tid] = o;
}

__global__ __launch_bounds__(256) void rowcount_kernel(float* __restrict__ wsf) {
    const int bs = blockIdx.x;
    const int b = bs >> 6, s = bs & 63;
    const int tid = threadIdx.x;
    unsigned int* cnts = (unsigned int*)wsf + WOFF_CNT;
    const float* nb = wsf + WOFF_NORM + (size_t)b * 65536;

    __shared__ __align__(16) float rowv[1024];
    *(float4*)&rowv[tid * 4] = *(const float4*)&nb[s * 1024 + tid * 4];
    __syncthreads();

    const int t = tid >> 2, part = tid & 3;
    const float4* src  = (const float4*)(nb + t * 1024 + part * 256);
    const float4* mine = (const float4*)(rowv + part * 256);
    float acc = 0.0f;
    #pragma unroll 8
    for (int i = 0; i < 64; ++i) {
        float4 a = mine[i];
        float4 bb = src[i];
        acc += a.x * bb.x + a.y * bb.y + a.z * bb.z + a.w * bb.w;
    }
    acc += __shfl_down(acc, 2);
    acc += __shfl_down(acc, 1);
    const float corrv = acc * (1.0f / 1024.0f);
    const bool valid = (part == 0) && (t != s);
    unsigned long long mthr = __ballot(valid && (corrv > 0.6f));
    unsigned long long mpos = __ballot(valid && (corrv > 0.0f));
    if ((tid & 63) == 0) {
        atomicAdd(&cnts[b],     (unsigned int)__popcll(mthr));
        atomicAdd(&cnts[8 + b], (unsigned int)__popcll(mpos));
    }
}

// ---------------- parallel pack: 64 blocks ----------------
// bid 0..47 : conv slice (dir = bid/24, ks = bid%24) -> cwt [ks][256 o][32 kk] f16
// bid 48..55: W1 slice   (dir, ks = 0..3)            -> w1t [ks][256 o][32 kk] f16
// bid 56..63: v = W2@Wr  (dir = (bid-56)>>2, quarter rows); bid 56 tid 0: strat+const
__global__ __launch_bounds__(256) void pack_kernel(
    const float* __restrict__ W2f, const float* __restrict__ b2f,
    const float* __restrict__ W2b, const float* __restrict__ b2b,
    const float* __restrict__ Wr,  const float* __restrict__ br,
    const float* __restrict__ W1f, const float* __restrict__ W1b,
    const float* __restrict__ Cwf, const float* __restrict__ Cwb,
    float* __restrict__ wsf) {
    const int bid = blockIdx.x;
    const int tid = threadIdx.x;

    if (bid < 48) {
        const int d = bid / 24, ks = bid % 24;
        const float* Cw = d ? Cwb : Cwf;
        fp16_t* cwt = (fp16_t*)(wsf + WOFF_CWT) + d * 196608;
        const int base = ks * 32;
        const int k = base >> 8, i0 = base & 255;
        fp16x8 v[4];
        #pragma unroll
        for (int j = 0; j < 4; ++j)
            #pragma unroll
            for (int e = 0; e < 8; ++e)
                v[j][e] = (fp16_t)Cw[(tid * 256 + i0 + j * 8 + e) * 3 + k];
        fp16x8* dst = (fp16x8*)(cwt + (ks * 256 + tid) * 32);
        dst[0] = v[0]; dst[1] = v[1]; dst[2] = v[2]; dst[3] = v[3];
    } else if (bid < 56) {
        const int sl = bid - 48;
        const int d = sl >> 2, ks = sl & 3;
        const float* W1 = d ? W1b : W1f;
        fp16_t* w1t = (fp16_t*)(wsf + WOFF_W1T) + d * 32768;
        fp16x8 v[4];
        #pragma unroll
        for (int j = 0; j < 4; ++j)
            #pragma unroll
            for (int e = 0; e < 8; ++e)
                v[j][e] = (fp16_t)W1[(ks * 32 + j * 8 + e) * 256 + tid];
        fp16x8* dst = (fp16x8*)(w1t + (ks * 256 + tid) * 32);
        dst[0] = v[0]; dst[1] = v[1]; dst[2] = v[2]; dst[3] = v[3];
    } else {
        const int vb = bid - 56;
        const int d = vb >> 2, q = vb & 3;
        const int w = tid >> 6, lane = tid & 63;
        const float* W2 = d ? W2b : W2f;
        float4 wr4 = ((const float4*)Wr)[lane];
        for (int it = 0; it < 16; ++it) {
            int row = q * 64 + w * 16 + it;
            float4 a = ((const float4*)(W2 + row * 256))[lane];
            float p = a.x * wr4.x + a.y * wr4.y + a.z * wr4.z + a.w * wr4.w;
            #pragma unroll
            for (int off = 32; off > 0; off >>= 1) p += __shfl_down(p, off);
            if (lane == 0) wsf[(d ? WOFF_VB : WOFF_VF) + row] = p;
        }
        if (bid == 56 && tid == 0) {
            const unsigned int* cnts = (const unsigned int*)wsf + WOFF_CNT;
            int* strat = (int*)wsf + WOFF_STRAT;
            float cc = 0.0f;
            for (int g = 0; g < 256; ++g) cc += (b2f[g] + b2b[g]) * Wr[g];
            wsf[WOFF_CONST] = cc + br[0];
            for (int bb = 0; bb < 8; ++bb) {
                unsigned int ct = cnts[bb], cp = cnts[8 + bb];
                unsigned int denom = cp < 1u ? 1u : cp;
                float ratio = (cp > 0u) ? ((float)ct / (float)denom) : 0.0f;
                strat[bb] = (ratio >= 0.4f) ? 1 : 0;
            }
        }
    }
}

// ---------------- fused main (MFMA, slice-prefetch pipelined) ----------------
__global__ __launch_bounds__(256, 3) void fused_main(
    const float* __restrict__ x,
    const float* __restrict__ b1f, const float* __restrict__ Cbf,
    const float* __restrict__ b1b, const float* __restrict__ Cbb,
    const float* __restrict__ wsf,
    float* __restrict__ out) {
    __shared__ __align__(16) char hbytes[66 * 512];  // h [66][256] f16, XOR-swizzled
    __shared__ __align__(16) char bsl[256 * 80];     // weight k-slice, 80B rows
    __shared__ float red[64];

    const int tid  = threadIdx.x;
    const int w    = tid >> 6;
    const int lane = tid & 63;
    const int l15  = lane & 15;
    const int l4   = lane >> 4;

    const int mb = blockIdx.x;
    const int b  = mb >> 8;
    const int n  = (mb >> 6) & 3;
    const int s  = mb & 63;
    const size_t bn = (size_t)(b * 4 + n);

    const int strat = ((const int*)wsf)[WOFF_STRAT + b];

    if (tid < 64) red[tid] = 0.0f;
    ((unsigned int*)(hbytes + 64 * 512))[tid] = 0u;  // zero pad rows 64,65

    const char* w1base = (const char*)(wsf + WOFF_W1T);
    const char* cwbase = (const char*)(wsf + WOFF_CWT);

    // prefetch first GEMM1 slice (dir 0)
    uint4 r0, r1, r2, r3;
    {
        const uint4* src = (const uint4*)(w1base + tid * 64);
        r0 = src[0]; r1 = src[1]; r2 = src[2]; r3 = src[3];
    }

    for (int dir = 0; dir < 2; ++dir) {
        const int sg = dir ? (63 - s) : s;
        const float* b1 = dir ? b1b : b1f;
        const float* cb = dir ? Cbb : Cbf;
        const char* w1sl = w1base + dir * 65536;
        const char* cwsl = cwbase + dir * 393216;

        float b1v[4], cbv[4], vv[4];
        #pragma unroll
        for (int t = 0; t < 4; ++t) {
            int col = w * 64 + t * 16 + l15;
            b1v[t] = b1[col];
            cbv[t] = cb[col];
            vv[t]  = wsf[(dir ? WOFF_VB : WOFF_VF) + col];
        }

        // ---------- GEMM1: K=128, 4 k-slices ----------
        f32x4 acc1[4][4];
        #pragma unroll
        for (int i = 0; i < 4; ++i)
            #pragma unroll
            for (int j = 0; j < 4; ++j)
                acc1[i][j] = (f32x4){0.f, 0.f, 0.f, 0.f};

        for (int ks = 0; ks < 4; ++ks) {
            __syncthreads();   // prev MFMA done -> bsl free
            uint4* dst = (uint4*)(bsl + tid * 80);
            dst[0] = r0; dst[1] = r1; dst[2] = r2; dst[3] = r3;
            fp16x8 af[4];
            #pragma unroll
            for (int mt = 0; mt < 4; ++mt) {
                int lp  = mt * 16 + l15;
                int r1i = strat ? lp : sg;
                int r2i = strat ? sg : lp;
                const float* xp = x + ((bn * 64 + r1i) * 8192
                                       + (size_t)r2i * 128 + ks * 32 + l4 * 8);
                float4 p0 = *(const float4*)xp;
                float4 p1 = *(const float4*)(xp + 4);
                fp16x8 a;
                a[0] = (fp16_t)p0.x; a[1] = (fp16_t)p0.y;
                a[2] = (fp16_t)p0.z; a[3] = (fp16_t)p0.w;
                a[4] = (fp16_t)p1.x; a[5] = (fp16_t)p1.y;
                a[6] = (fp16_t)p1.z; a[7] = (fp16_t)p1.w;
                af[mt] = a;
            }
            // prefetch next slice (GEMM1 ks+1, or conv slice 0)
            {
                const char* np = (ks < 3) ? (w1sl + (ks + 1) * 16384) : cwsl;
                const uint4* src = (const uint4*)(np + tid * 64);
                r0 = src[0]; r1 = src[1]; r2 = src[2]; r3 = src[3];
            }
            __syncthreads();   // slice ready
            #pragma unroll
            for (int t = 0; t < 4; ++t) {
                int o = w * 64 + t * 16 + l15;
                fp16x8 bf = *(const fp16x8*)(bsl + o * 80 + l4 * 16);
                #pragma unroll
                for (int mt = 0; mt < 4; ++mt)
                    acc1[mt][t] = __builtin_amdgcn_mfma_f32_16x16x32_f16(
                        af[mt], bf, acc1[mt][t], 0, 0, 0);
            }
        }

        // h = silu(acc + b1) -> LDS f16, XOR-swizzled rows
        #pragma unroll
        for (int mt = 0; mt < 4; ++mt) {
            #pragma unroll
            for (int t = 0; t < 4; ++t) {
                int col = w * 64 + t * 16 + l15;
                #pragma unroll
                for (int q = 0; q < 4; ++q) {
                    int row = mt * 16 + l4 * 4 + q;
                    float hv = silu_f(acc1[mt][t][q] + b1v[t]);
                    int off = (row * 512 + col * 2) ^ ((row & 7) << 4);
                    *(fp16_t*)(hbytes + off) = (fp16_t)hv;
                }
            }
        }

        // ---------- conv GEMM: K=768, 24 k-slices ----------
        f32x4 acc2[4][4];
        #pragma unroll
        for (int i = 0; i < 4; ++i)
            #pragma unroll
            for (int j = 0; j < 4; ++j)
                acc2[i][j] = (f32x4){0.f, 0.f, 0.f, 0.f};

        for (int ks = 0; ks < 24; ++ks) {
            __syncthreads();   // prev MFMA done (and h writes done at ks=0)
            uint4* dst = (uint4*)(bsl + tid * 80);
            dst[0] = r0; dst[1] = r1; dst[2] = r2; dst[3] = r3;
            fp16x8 af[4];
            #pragma unroll
            for (int mt = 0; mt < 4; ++mt) {
                int l  = mt * 16 + l15;
                int fb = l * 512 + ks * 64 + l4 * 16;
                int ad = fb ^ (((fb >> 9) & 7) << 4);
                af[mt] = *(const fp16x8*)(hbytes + ad);
            }
            // prefetch next slice (conv ks+1, or next dir's W1 slice 0)
            if (ks < 23) {
                const uint4* src = (const uint4*)(cwsl + (ks + 1) * 16384 + tid * 64);
                r0 = src[0]; r1 = src[1]; r2 = src[2]; r3 = src[3];
            } else if (dir == 0) {
                const uint4* src = (const uint4*)(w1base + 65536 + tid * 64);
                r0 = src[0]; r1 = src[1]; r2 = src[2]; r3 = src[3];
            }
            __syncthreads();   // slice ready
            #pragma unroll
            for (int t = 0; t < 4; ++t) {
                int o = w * 64 + t * 16 + l15;
                fp16x8 bf = *(const fp16x8*)(bsl + o * 80 + l4 * 16);
                #pragma unroll
                for (int mt = 0; mt < 4; ++mt)
                    acc2[mt][t] = __builtin_amdgcn_mfma_f32_16x16x32_f16(
                        af[mt], bf, acc2[mt][t], 0, 0, 0);
            }
        }

        // epilogue: silu(conv + cb) * v, col-sum -> red[row]
        #pragma unroll
        for (int mt = 0; mt < 4; ++mt) {
            #pragma unroll
            for (int q = 0; q < 4; ++q) {
                float v0 = 0.f;
                #pragma unroll
                for (int t = 0; t < 4; ++t)
                    v0 += silu_f(acc2[mt][t][q] + cbv[t]) * vv[t];
                v0 += __shfl_xor(v0, 1);
                v0 += __shfl_xor(v0, 2);
                v0 += __shfl_xor(v0, 4);
                v0 += __shfl_xor(v0, 8);
                if (l15 == 0) {
                    int row = mt * 16 + l4 * 4 + q;
                    atomicAdd(&red[row], v0);
                }
            }
        }
    }

    __syncthreads();
    if (tid < 62)
        out[(bn * 64 + s) * 62 + tid] = red[tid] + wsf[WOFF_CONST];
}

extern "C" void kernel_launch(void* const* d_in, const int* in_sizes, int n_in,
                              void* d_out, int out_size, void* d_ws, size_t ws_size,
                              hipStream_t stream) {
    (void)in_sizes; (void)n_in; (void)out_size; (void)ws_size;
    const float* x    = (const float*)d_in[0];
    const float* corr = (const float*)d_in[1];
    const float* W1f  = (const float*)d_in[2];
    const float* b1f  = (const float*)d_in[3];
    const float* Cwf  = (const float*)d_in[4];
    const float* Cbf  = (const float*)d_in[5];
    const float* W2f  = (const float*)d_in[6];
    const float* b2f  = (const float*)d_in[7];
    const float* W1b  = (const float*)d_in[8];
    const float* b1b  = (const float*)d_in[9];
    const float* Cwb  = (const float*)d_in[10];
    const float* Cbb  = (const float*)d_in[11];
    const float* W2b  = (const float*)d_in[12];
    const float* b2b  = (const float*)d_in[13];
    const float* Wr   = (const float*)d_in[14];
    const float* br   = (const float*)d_in[15];
    float* out = (float*)d_out;
    float* wsf = (float*)d_ws;

    norm_kernel<<<512, 256, 0, stream>>>(corr, wsf);
    rowcount_kernel<<<512, 256, 0, stream>>>(wsf);
    pack_kernel<<<64, 256, 0, stream>>>(W2f, b2f, W2b, b2b, Wr, br,
                                        W1f, W1b, Cwf, Cwb, wsf);
    fused_main<<<2048, 256, 0, stream>>>(x, b1f, Cbf, b1b, Cbb, wsf, out);
}

// Round 4
// 306.398 us; speedup vs baseline: 9.3379x; 1.5388x over previous
//
#include <hip/hip_runtime.h>
#include <hip/hip_bf16.h>

// ---------------- problem constants ----------------
// x: [B=8, N1=4, S=64, L=8192], PATCH=128 -> Lp=64, P=128, F=256, Lout=62
// out: [8,4,64,62,1] fp32

typedef _Float16 fp16_t;
typedef _Float16 fp16x8 __attribute__((ext_vector_type(8)));
typedef float f32x4 __attribute__((ext_vector_type(4)));

// ws float-word offsets
constexpr int WOFF_CNT   = 0;     // 16 uints
constexpr int WOFF_STRAT = 16;    // 8 ints
constexpr int WOFF_CONST = 32;    // 1 float
constexpr int WOFF_VF    = 64;    // 256 floats
constexpr int WOFF_VB    = 320;   // 256 floats
constexpr int WOFF_NORM  = 1024;                // 8*64*1024 floats
constexpr int WOFF_W1T   = WOFF_NORM + 524288;  // f16 [2][4][256][32]
constexpr int WOFF_CWT   = WOFF_W1T + 32768;    // f16 [2][24][256][32]

__device__ __forceinline__ float silu_f(float v) {
    return v / (1.0f + __expf(-v));
}

// ---------------- decide stage (unchanged, verified) ----------------
__global__ __launch_bounds__(256) void norm_kernel(const float* __restrict__ c,
                                                   float* __restrict__ wsf) {
    const int bs = blockIdx.x;
    const int tid = threadIdx.x;
    unsigned int* cnts = (unsigned int*)wsf + WOFF_CNT;
    if (bs == 0 && tid < 16) cnts[tid] = 0u;

    const float* row = c + (size_t)bs * 1024;
    float4 v = ((const float4*)row)[tid];
    float sum = v.x + v.y + v.z + v.w;
    float sq  = v.x*v.x + v.y*v.y + v.z*v.z + v.w*v.w;
    #pragma unroll
    for (int off = 32; off > 0; off >>= 1) {
        sum += __shfl_down(sum, off);
        sq  += __shfl_down(sq, off);
    }
    __shared__ float ls[8];
    __shared__ float stats[2];
    const int w = tid >> 6;
    if ((tid & 63) == 0) { ls[w] = sum; ls[4 + w] = sq; }
    __syncthreads();
    if (tid == 0) {
        float S = ls[0] + ls[1] + ls[2] + ls[3];
        float Q = ls[4] + ls[5] + ls[6] + ls[7];
        float mean = S * (1.0f / 1024.0f);
        float var  = (Q - 1024.0f * mean * mean) * (1.0f / 1023.0f);
        stats[0] = mean;
        stats[1] = 1.0f / sqrtf(var);
    }
    __syncthreads();
    const float mean = stats[0], inv = stats[1];
    float4 o;
    o.x = (v.x - mean) * inv; o.y = (v.y - mean) * inv;
    o.z = (v.z - mean) * inv; o.w = (v.w - mean) * inv;
    ((float4*)(wsf + WOFF_NORM + (size_t)bs * 1024))[tid] = o;
}

__global__ __launch_bounds__(256) void rowcount_kernel(float* __restrict__ wsf) {
    const int bs = blockIdx.x;
    const int b = bs >> 6, s = bs & 63;
    const int tid = threadIdx.x;
    unsigned int* cnts = (unsigned int*)wsf + WOFF_CNT;
    const float* nb = wsf + WOFF_NORM + (size_t)b * 65536;

    __shared__ __align__(16) float rowv[1024];
    *(float4*)&rowv[tid * 4] = *(const float4*)&nb[s * 1024 + tid * 4];
    __syncthreads();

    const int t = tid >> 2, part = tid & 3;
    const float4* src  = (const float4*)(nb + t * 1024 + part * 256);
    const float4* mine = (const float4*)(rowv + part * 256);
    float acc = 0.0f;
    #pragma unroll 8
    for (int i = 0; i < 64; ++i) {
        float4 a = mine[i];
        float4 bb = src[i];
        acc += a.x * bb.x + a.y * bb.y + a.z * bb.z + a.w * bb.w;
    }
    acc += __shfl_down(acc, 2);
    acc += __shfl_down(acc, 1);
    const float corrv = acc * (1.0f / 1024.0f);
    const bool valid = (part == 0) && (t != s);
    unsigned long long mthr = __ballot(valid && (corrv > 0.6f));
    unsigned long long mpos = __ballot(valid && (corrv > 0.0f));
    if ((tid & 63) == 0) {
        atomicAdd(&cnts[b],     (unsigned int)__popcll(mthr));
        atomicAdd(&cnts[8 + b], (unsigned int)__popcll(mpos));
    }
}

// ---------------- parallel pack: 64 blocks (unchanged, verified) ----------------
__global__ __launch_bounds__(256) void pack_kernel(
    const float* __restrict__ W2f, const float* __restrict__ b2f,
    const float* __restrict__ W2b, const float* __restrict__ b2b,
    const float* __restrict__ Wr,  const float* __restrict__ br,
    const float* __restrict__ W1f, const float* __restrict__ W1b,
    const float* __restrict__ Cwf, const float* __restrict__ Cwb,
    float* __restrict__ wsf) {
    const int bid = blockIdx.x;
    const int tid = threadIdx.x;

    if (bid < 48) {
        const int d = bid / 24, ks = bid % 24;
        const float* Cw = d ? Cwb : Cwf;
        fp16_t* cwt = (fp16_t*)(wsf + WOFF_CWT) + d * 196608;
        const int base = ks * 32;
        const int k = base >> 8, i0 = base & 255;
        fp16x8 v[4];
        #pragma unroll
        for (int j = 0; j < 4; ++j)
            #pragma unroll
            for (int e = 0; e < 8; ++e)
                v[j][e] = (fp16_t)Cw[(tid * 256 + i0 + j * 8 + e) * 3 + k];
        fp16x8* dst = (fp16x8*)(cwt + (ks * 256 + tid) * 32);
        dst[0] = v[0]; dst[1] = v[1]; dst[2] = v[2]; dst[3] = v[3];
    } else if (bid < 56) {
        const int sl = bid - 48;
        const int d = sl >> 2, ks = sl & 3;
        const float* W1 = d ? W1b : W1f;
        fp16_t* w1t = (fp16_t*)(wsf + WOFF_W1T) + d * 32768;
        fp16x8 v[4];
        #pragma unroll
        for (int j = 0; j < 4; ++j)
            #pragma unroll
            for (int e = 0; e < 8; ++e)
                v[j][e] = (fp16_t)W1[(ks * 32 + j * 8 + e) * 256 + tid];
        fp16x8* dst = (fp16x8*)(w1t + (ks * 256 + tid) * 32);
        dst[0] = v[0]; dst[1] = v[1]; dst[2] = v[2]; dst[3] = v[3];
    } else {
        const int vb = bid - 56;
        const int d = vb >> 2, q = vb & 3;
        const int w = tid >> 6, lane = tid & 63;
        const float* W2 = d ? W2b : W2f;
        float4 wr4 = ((const float4*)Wr)[lane];
        for (int it = 0; it < 16; ++it) {
            int row = q * 64 + w * 16 + it;
            float4 a = ((const float4*)(W2 + row * 256))[lane];
            float p = a.x * wr4.x + a.y * wr4.y + a.z * wr4.z + a.w * wr4.w;
            #pragma unroll
            for (int off = 32; off > 0; off >>= 1) p += __shfl_down(p, off);
            if (lane == 0) wsf[(d ? WOFF_VB : WOFF_VF) + row] = p;
        }
        if (bid == 56 && tid == 0) {
            const unsigned int* cnts = (const unsigned int*)wsf + WOFF_CNT;
            int* strat = (int*)wsf + WOFF_STRAT;
            float cc = 0.0f;
            for (int g = 0; g < 256; ++g) cc += (b2f[g] + b2b[g]) * Wr[g];
            wsf[WOFF_CONST] = cc + br[0];
            for (int bb = 0; bb < 8; ++bb) {
                unsigned int ct = cnts[bb], cp = cnts[8 + bb];
                unsigned int denom = cp < 1u ? 1u : cp;
                float ratio = (cp > 0u) ? ((float)ct / (float)denom) : 0.0f;
                strat[bb] = (ratio >= 0.4f) ? 1 : 0;
            }
        }
    }
}

// ---------------- fused main (MFMA, B direct-from-global, barrier-free loops) ----
// 1 block per (b,n,s), 4 waves. Wave w owns output cols [64w, 64w+64).
// B-fragments are contiguous coalesced 1KB/wave global reads, L2-resident.
__global__ __launch_bounds__(256, 3) void fused_main(
    const float* __restrict__ x,
    const float* __restrict__ b1f, const float* __restrict__ Cbf,
    const float* __restrict__ b1b, const float* __restrict__ Cbb,
    const float* __restrict__ wsf,
    float* __restrict__ out) {
    __shared__ __align__(16) char hbytes[66 * 512];  // h [66][256] f16, XOR-swizzled
    __shared__ float red[64];

    const int tid  = threadIdx.x;
    const int w    = tid >> 6;
    const int lane = tid & 63;
    const int l15  = lane & 15;
    const int l4   = lane >> 4;

    const int mb = blockIdx.x;
    const int b  = mb >> 8;
    const int n  = (mb >> 6) & 3;
    const int s  = mb & 63;
    const size_t bn = (size_t)(b * 4 + n);

    const int strat = ((const int*)wsf)[WOFF_STRAT + b];

    if (tid < 64) red[tid] = 0.0f;
    ((unsigned int*)(hbytes + 64 * 512))[tid] = 0u;  // zero pad rows 64,65

    const char* w1base = (const char*)(wsf + WOFF_W1T);
    const char* cwbase = (const char*)(wsf + WOFF_CWT);

    for (int dir = 0; dir < 2; ++dir) {
        const int sg = dir ? (63 - s) : s;
        const float* b1 = dir ? b1b : b1f;
        const float* cb = dir ? Cbb : Cbf;
        const char* w1sl = w1base + dir * 65536;
        const char* cwsl = cwbase + dir * 393216;

        float b1v[4], cbv[4], vv[4];
        #pragma unroll
        for (int t = 0; t < 4; ++t) {
            int col = w * 64 + t * 16 + l15;
            b1v[t] = b1[col];
            cbv[t] = cb[col];
            vv[t]  = wsf[(dir ? WOFF_VB : WOFF_VF) + col];
        }

        // ---------- GEMM1: K=128, 4 k-slices, no barriers ----------
        f32x4 acc1[4][4];
        #pragma unroll
        for (int i = 0; i < 4; ++i)
            #pragma unroll
            for (int j = 0; j < 4; ++j)
                acc1[i][j] = (f32x4){0.f, 0.f, 0.f, 0.f};

        for (int ks = 0; ks < 4; ++ks) {
            fp16x8 af[4];
            #pragma unroll
            for (int mt = 0; mt < 4; ++mt) {
                int lp  = mt * 16 + l15;
                int r1i = strat ? lp : sg;
                int r2i = strat ? sg : lp;
                const float* xp = x + ((bn * 64 + r1i) * 8192
                                       + (size_t)r2i * 128 + ks * 32 + l4 * 8);
                float4 p0 = *(const float4*)xp;
                float4 p1 = *(const float4*)(xp + 4);
                fp16x8 a;
                a[0] = (fp16_t)p0.x; a[1] = (fp16_t)p0.y;
                a[2] = (fp16_t)p0.z; a[3] = (fp16_t)p0.w;
                a[4] = (fp16_t)p1.x; a[5] = (fp16_t)p1.y;
                a[6] = (fp16_t)p1.z; a[7] = (fp16_t)p1.w;
                af[mt] = a;
            }
            #pragma unroll
            for (int t = 0; t < 4; ++t) {
                fp16x8 bf = *(const fp16x8*)(w1sl
                    + (ks * 256 + w * 64 + t * 16 + l15) * 64 + l4 * 16);
                #pragma unroll
                for (int mt = 0; mt < 4; ++mt)
                    acc1[mt][t] = __builtin_amdgcn_mfma_f32_16x16x32_f16(
                        af[mt], bf, acc1[mt][t], 0, 0, 0);
            }
        }

        // barrier: all waves done reading prev dir's hbytes before overwrite
        __syncthreads();
        #pragma unroll
        for (int mt = 0; mt < 4; ++mt) {
            #pragma unroll
            for (int t = 0; t < 4; ++t) {
                int col = w * 64 + t * 16 + l15;
                #pragma unroll
                for (int q = 0; q < 4; ++q) {
                    int row = mt * 16 + l4 * 4 + q;
                    float hv = silu_f(acc1[mt][t][q] + b1v[t]);
                    int off = (row * 512 + col * 2) ^ ((row & 7) << 4);
                    *(fp16_t*)(hbytes + off) = (fp16_t)hv;
                }
            }
        }
        __syncthreads();

        // ---------- conv GEMM: K=768, 24 k-slices, no barriers ----------
        f32x4 acc2[4][4];
        #pragma unroll
        for (int i = 0; i < 4; ++i)
            #pragma unroll
            for (int j = 0; j < 4; ++j)
                acc2[i][j] = (f32x4){0.f, 0.f, 0.f, 0.f};

        const int wb = (w * 64 + l15) * 64 + l4 * 16;  // wave/lane B base (t stride 1024)
        fp16x8 bq[4];
        #pragma unroll
        for (int t = 0; t < 4; ++t)
            bq[t] = *(const fp16x8*)(cwsl + wb + t * 1024);

        for (int ks = 0; ks < 24; ++ks) {
            fp16x8 bnx[4];
            if (ks < 23) {
                #pragma unroll
                for (int t = 0; t < 4; ++t)
                    bnx[t] = *(const fp16x8*)(cwsl + (ks + 1) * 16384 + wb + t * 1024);
            }
            fp16x8 af[4];
            #pragma unroll
            for (int mt = 0; mt < 4; ++mt) {
                int l  = mt * 16 + l15;
                int fb = l * 512 + ks * 64 + l4 * 16;
                int ad = fb ^ (((fb >> 9) & 7) << 4);
                af[mt] = *(const fp16x8*)(hbytes + ad);
            }
            #pragma unroll
            for (int t = 0; t < 4; ++t)
                #pragma unroll
                for (int mt = 0; mt < 4; ++mt)
                    acc2[mt][t] = __builtin_amdgcn_mfma_f32_16x16x32_f16(
                        af[mt], bq[t], acc2[mt][t], 0, 0, 0);
            #pragma unroll
            for (int t = 0; t < 4; ++t) bq[t] = bnx[t];
        }

        // epilogue: silu(conv + cb) * v, col-sum -> red[row]
        #pragma unroll
        for (int mt = 0; mt < 4; ++mt) {
            #pragma unroll
            for (int q = 0; q < 4; ++q) {
                float v0 = 0.f;
                #pragma unroll
                for (int t = 0; t < 4; ++t)
                    v0 += silu_f(acc2[mt][t][q] + cbv[t]) * vv[t];
                v0 += __shfl_xor(v0, 1);
                v0 += __shfl_xor(v0, 2);
                v0 += __shfl_xor(v0, 4);
                v0 += __shfl_xor(v0, 8);
                if (l15 == 0) {
                    int row = mt * 16 + l4 * 4 + q;
                    atomicAdd(&red[row], v0);
                }
            }
        }
    }

    __syncthreads();
    if (tid < 62)
        out[(bn * 64 + s) * 62 + tid] = red[tid] + wsf[WOFF_CONST];
}

extern "C" void kernel_launch(void* const* d_in, const int* in_sizes, int n_in,
                              void* d_out, int out_size, void* d_ws, size_t ws_size,
                              hipStream_t stream) {
    (void)in_sizes; (void)n_in; (void)out_size; (void)ws_size;
    const float* x    = (const float*)d_in[0];
    const float* corr = (const float*)d_in[1];
    const float* W1f  = (const float*)d_in[2];
    const float* b1f  = (const float*)d_in[3];
    const float* Cwf  = (const float*)d_in[4];
    const float* Cbf  = (const float*)d_in[5];
    const float* W2f  = (const float*)d_in[6];
    const float* b2f  = (const float*)d_in[7];
    const float* W1b  = (const float*)d_in[8];
    const float* b1b  = (const float*)d_in[9];
    const float* Cwb  = (const float*)d_in[10];
    const float* Cbb  = (const float*)d_in[11];
    const float* W2b  = (const float*)d_in[12];
    const float* b2b  = (const float*)d_in[13];
    const float* Wr   = (const float*)d_in[14];
    const float* br   = (const float*)d_in[15];
    float* out = (float*)d_out;
    float* wsf = (float*)d_ws;

    norm_kernel<<<512, 256, 0, stream>>>(corr, wsf);
    rowcount_kernel<<<512, 256, 0, stream>>>(wsf);
    pack_kernel<<<64, 256, 0, stream>>>(W2f, b2f, W2b, b2b, Wr, br,
                                        W1f, W1b, Cwf, Cwb, wsf);
    fused_main<<<2048, 256, 0, stream>>>(x, b1f, Cbf, b1b, Cbb, wsf, out);
}

// Round 6
// 264.035 us; speedup vs baseline: 10.8361x; 1.1604x over previous
//
#include <hip/hip_runtime.h>
#include <hip/hip_bf16.h>

// ---------------- problem constants ----------------
// x: [B=8, N1=4, S=64, L=8192], PATCH=128 -> Lp=64, P=128, F=256, Lout=62
// out: [8,4,64,62,1] fp32

typedef _Float16 fp16_t;
typedef _Float16 fp16x8 __attribute__((ext_vector_type(8)));
typedef __fp16 pkh2 __attribute__((ext_vector_type(2)));   // cvt_pkrtz result type
typedef float f32x4 __attribute__((ext_vector_type(4)));

// ws float-word offsets
constexpr int WOFF_CNT   = 0;     // 16 uints
constexpr int WOFF_STRAT = 16;    // 8 ints
constexpr int WOFF_CONST = 32;    // 1 float
constexpr int WOFF_VF    = 64;    // 256 floats
constexpr int WOFF_VB    = 320;   // 256 floats
constexpr int WOFF_NORM  = 1024;                // 8*64*1024 floats
constexpr int WOFF_W1T   = WOFF_NORM + 524288;  // f16 [2][4][256][32]
constexpr int WOFF_CWT   = WOFF_W1T + 32768;    // f16 [2][24][256][32]

constexpr int HSTRIDE = 528;          // 264 f16 per row (256 + 8 pad)
constexpr int HBUF    = 66 * HSTRIDE; // 34848 B per s-half

__device__ __forceinline__ float silu_f(float v) {
    return v / (1.0f + __expf(-v));
}

// ---------------- decide stage (unchanged, verified) ----------------
__global__ __launch_bounds__(256) void norm_kernel(const float* __restrict__ c,
                                                   float* __restrict__ wsf) {
    const int bs = blockIdx.x;
    const int tid = threadIdx.x;
    unsigned int* cnts = (unsigned int*)wsf + WOFF_CNT;
    if (bs == 0 && tid < 16) cnts[tid] = 0u;

    const float* row = c + (size_t)bs * 1024;
    float4 v = ((const float4*)row)[tid];
    float sum = v.x + v.y + v.z + v.w;
    float sq  = v.x*v.x + v.y*v.y + v.z*v.z + v.w*v.w;
    #pragma unroll
    for (int off = 32; off > 0; off >>= 1) {
        sum += __shfl_down(sum, off);
        sq  += __shfl_down(sq, off);
    }
    __shared__ float ls[8];
    __shared__ float stats[2];
    const int w = tid >> 6;
    if ((tid & 63) == 0) { ls[w] = sum; ls[4 + w] = sq; }
    __syncthreads();
    if (tid == 0) {
        float S = ls[0] + ls[1] + ls[2] + ls[3];
        float Q = ls[4] + ls[5] + ls[6] + ls[7];
        float mean = S * (1.0f / 1024.0f);
        float var  = (Q - 1024.0f * mean * mean) * (1.0f / 1023.0f);
        stats[0] = mean;
        stats[1] = 1.0f / sqrtf(var);
    }
    __syncthreads();
    const float mean = stats[0], inv = stats[1];
    float4 o;
    o.x = (v.x - mean) * inv; o.y = (v.y - mean) * inv;
    o.z = (v.z - mean) * inv; o.w = (v.w - mean) * inv;
    ((float4*)(wsf + WOFF_NORM + (size_t)bs * 1024))[tid] = o;
}

__global__ __launch_bounds__(256) void rowcount_kernel(float* __restrict__ wsf) {
    const int bs = blockIdx.x;
    const int b = bs >> 6, s = bs & 63;
    const int tid = threadIdx.x;
    unsigned int* cnts = (unsigned int*)wsf + WOFF_CNT;
    const float* nb = wsf + WOFF_NORM + (size_t)b * 65536;

    __shared__ __align__(16) float rowv[1024];
    *(float4*)&rowv[tid * 4] = *(const float4*)&nb[s * 1024 + tid * 4];
    __syncthreads();

    const int t = tid >> 2, part = tid & 3;
    const float4* src  = (const float4*)(nb + t * 1024 + part * 256);
    const float4* mine = (const float4*)(rowv + part * 256);
    float acc = 0.0f;
    #pragma unroll 8
    for (int i = 0; i < 64; ++i) {
        float4 a = mine[i];
        float4 bb = src[i];
        acc += a.x * bb.x + a.y * bb.y + a.z * bb.z + a.w * bb.w;
    }
    acc += __shfl_down(acc, 2);
    acc += __shfl_down(acc, 1);
    const float corrv = acc * (1.0f / 1024.0f);
    const bool valid = (part == 0) && (t != s);
    unsigned long long mthr = __ballot(valid && (corrv > 0.6f));
    unsigned long long mpos = __ballot(valid && (corrv > 0.0f));
    if ((tid & 63) == 0) {
        atomicAdd(&cnts[b],     (unsigned int)__popcll(mthr));
        atomicAdd(&cnts[8 + b], (unsigned int)__popcll(mpos));
    }
}

// ---------------- parallel pack: 64 blocks (unchanged, verified) ----------------
__global__ __launch_bounds__(256) void pack_kernel(
    const float* __restrict__ W2f, const float* __restrict__ b2f,
    const float* __restrict__ W2b, const float* __restrict__ b2b,
    const float* __restrict__ Wr,  const float* __restrict__ br,
    const float* __restrict__ W1f, const float* __restrict__ W1b,
    const float* __restrict__ Cwf, const float* __restrict__ Cwb,
    float* __restrict__ wsf) {
    const int bid = blockIdx.x;
    const int tid = threadIdx.x;

    if (bid < 48) {
        const int d = bid / 24, ks = bid % 24;
        const float* Cw = d ? Cwb : Cwf;
        fp16_t* cwt = (fp16_t*)(wsf + WOFF_CWT) + d * 196608;
        const int base = ks * 32;
        const int k = base >> 8, i0 = base & 255;
        fp16x8 v[4];
        #pragma unroll
        for (int j = 0; j < 4; ++j)
            #pragma unroll
            for (int e = 0; e < 8; ++e)
                v[j][e] = (fp16_t)Cw[(tid * 256 + i0 + j * 8 + e) * 3 + k];
        fp16x8* dst = (fp16x8*)(cwt + (ks * 256 + tid) * 32);
        dst[0] = v[0]; dst[1] = v[1]; dst[2] = v[2]; dst[3] = v[3];
    } else if (bid < 56) {
        const int sl = bid - 48;
        const int d = sl >> 2, ks = sl & 3;
        const float* W1 = d ? W1b : W1f;
        fp16_t* w1t = (fp16_t*)(wsf + WOFF_W1T) + d * 32768;
        fp16x8 v[4];
        #pragma unroll
        for (int j = 0; j < 4; ++j)
            #pragma unroll
            for (int e = 0; e < 8; ++e)
                v[j][e] = (fp16_t)W1[(ks * 32 + j * 8 + e) * 256 + tid];
        fp16x8* dst = (fp16x8*)(w1t + (ks * 256 + tid) * 32);
        dst[0] = v[0]; dst[1] = v[1]; dst[2] = v[2]; dst[3] = v[3];
    } else {
        const int vb = bid - 56;
        const int d = vb >> 2, q = vb & 3;
        const int w = tid >> 6, lane = tid & 63;
        const float* W2 = d ? W2b : W2f;
        float4 wr4 = ((const float4*)Wr)[lane];
        for (int it = 0; it < 16; ++it) {
            int row = q * 64 + w * 16 + it;
            float4 a = ((const float4*)(W2 + row * 256))[lane];
            float p = a.x * wr4.x + a.y * wr4.y + a.z * wr4.z + a.w * wr4.w;
            #pragma unroll
            for (int off = 32; off > 0; off >>= 1) p += __shfl_down(p, off);
            if (lane == 0) wsf[(d ? WOFF_VB : WOFF_VF) + row] = p;
        }
        if (bid == 56 && tid == 0) {
            const unsigned int* cnts = (const unsigned int*)wsf + WOFF_CNT;
            int* strat = (int*)wsf + WOFF_STRAT;
            float cc = 0.0f;
            for (int g = 0; g < 256; ++g) cc += (b2f[g] + b2b[g]) * Wr[g];
            wsf[WOFF_CONST] = cc + br[0];
            for (int bb = 0; bb < 8; ++bb) {
                unsigned int ct = cnts[bb], cp = cnts[8 + bb];
                unsigned int denom = cp < 1u ? 1u : cp;
                float ratio = (cp > 0u) ? ((float)ct / (float)denom) : 0.0f;
                strat[bb] = (ratio >= 0.4f) ? 1 : 0;
            }
        }
    }
}

// ---------------- fused main: 2 s per block, M=128 per wave ----------------
// grid 1024 = (b, n, sp); 4 waves; wave w owns output cols [64w, 64w+64).
// GEMM1 swapped (A=W1, B=tok): D = h[l][f], lane packs 4 consecutive f -> b64 writes.
// conv: A = h rows (M=128 over two s-halves), B = weights direct from global (L2).
__global__ __launch_bounds__(256, 2) void fused_main(
    const float* __restrict__ x,
    const float* __restrict__ b1f, const float* __restrict__ Cbf,
    const float* __restrict__ b1b, const float* __restrict__ Cbb,
    const float* __restrict__ wsf,
    float* __restrict__ out) {
    __shared__ __align__(16) char hball[2 * HBUF];  // two h buffers, rows padded to 528B
    __shared__ float red[128];

    char* hb0 = hball;
    char* hb1 = hball + HBUF;

    const int tid  = threadIdx.x;
    const int w    = tid >> 6;
    const int lane = tid & 63;
    const int l15  = lane & 15;
    const int l4   = lane >> 4;

    const int mb = blockIdx.x;
    const int b  = mb >> 7;
    const int n  = (mb >> 5) & 3;
    const int sp = mb & 31;
    const int s0 = sp * 2, s1 = s0 + 1;
    const size_t bn = (size_t)(b * 4 + n);

    const int strat = ((const int*)wsf)[WOFF_STRAT + b];

    if (tid < 128) red[tid] = 0.0f;
    // zero pad rows 64,65 of both buffers (conv tail reads them)
    for (int i = tid; i < 528; i += 256) {
        if (i < 264) ((float*)(hb0 + 64 * HSTRIDE))[i] = 0.0f;
        else         ((float*)(hb1 + 64 * HSTRIDE))[i - 264] = 0.0f;
    }

    const char* w1base = (const char*)(wsf + WOFF_W1T);
    const char* cwbase = (const char*)(wsf + WOFF_CWT);

    for (int dir = 0; dir < 2; ++dir) {
        const float* b1 = dir ? b1b : b1f;
        const float* cb = dir ? Cbb : Cbf;
        const char* w1sl = w1base + dir * 65536;
        const char* cwsl = cwbase + dir * 393216;

        // per-t tok row base pointers (N-tiles: t 0..3 -> s0, 4..7 -> s1)
        const float* xbase[8];
        #pragma unroll
        for (int t = 0; t < 8; ++t) {
            int sv = (t < 4) ? s0 : s1;
            int sg = dir ? (63 - sv) : sv;
            int lp = (t & 3) * 16 + l15;
            int r1i = strat ? lp : sg;
            int r2i = strat ? sg : lp;
            xbase[t] = x + ((bn * 64 + r1i) * 8192 + (size_t)r2i * 128 + l4 * 8);
        }

        // ---------- GEMM1 (swapped): h[l][f] = silu(tok@W1 + b1) ----------
        f32x4 acc1[4][8];
        #pragma unroll
        for (int i = 0; i < 4; ++i)
            #pragma unroll
            for (int j = 0; j < 8; ++j)
                acc1[i][j] = (f32x4){0.f, 0.f, 0.f, 0.f};

        #pragma unroll
        for (int ks = 0; ks < 4; ++ks) {
            fp16x8 wa[4];   // A = W1 frags (M = f)
            #pragma unroll
            for (int mt = 0; mt < 4; ++mt)
                wa[mt] = *(const fp16x8*)(w1sl
                    + (ks * 256 + w * 64 + mt * 16 + l15) * 64 + l4 * 16);
            fp16x8 tb[8];   // B = tok frags (N = l)
            #pragma unroll
            for (int t = 0; t < 8; ++t) {
                const float* p = xbase[t] + ks * 32;
                float4 p0 = *(const float4*)p;
                float4 p1 = *(const float4*)(p + 4);
                union { fp16x8 v; pkh2 h2[4]; } u;
                u.h2[0] = __builtin_amdgcn_cvt_pkrtz(p0.x, p0.y);
                u.h2[1] = __builtin_amdgcn_cvt_pkrtz(p0.z, p0.w);
                u.h2[2] = __builtin_amdgcn_cvt_pkrtz(p1.x, p1.y);
                u.h2[3] = __builtin_amdgcn_cvt_pkrtz(p1.z, p1.w);
                tb[t] = u.v;
            }
            #pragma unroll
            for (int mt = 0; mt < 4; ++mt)
                #pragma unroll
                for (int t = 0; t < 8; ++t)
                    acc1[mt][t] = __builtin_amdgcn_mfma_f32_16x16x32_f16(
                        wa[mt], tb[t], acc1[mt][t], 0, 0, 0);
        }

        // bias values for this lane's f rows
        float b1r[4][4];
        #pragma unroll
        for (int mt = 0; mt < 4; ++mt)
            #pragma unroll
            for (int q = 0; q < 4; ++q)
                b1r[mt][q] = b1[w * 64 + mt * 16 + l4 * 4 + q];

        __syncthreads();  // prev dir's conv reads of h done
        #pragma unroll
        for (int t = 0; t < 8; ++t) {
            char* hbt = (t < 4) ? hb0 : hb1;
            int l = (t & 3) * 16 + l15;
            char* dst = hbt + l * HSTRIDE + (w * 64 + l4 * 4) * 2;
            #pragma unroll
            for (int mt = 0; mt < 4; ++mt) {
                f32x4 a = acc1[mt][t];
                union { pkh2 h2[2]; uint2 u; } pk;
                pk.h2[0] = __builtin_amdgcn_cvt_pkrtz(
                    silu_f(a[0] + b1r[mt][0]), silu_f(a[1] + b1r[mt][1]));
                pk.h2[1] = __builtin_amdgcn_cvt_pkrtz(
                    silu_f(a[2] + b1r[mt][2]), silu_f(a[3] + b1r[mt][3]));
                *(uint2*)(dst + mt * 32) = pk.u;
            }
        }
        __syncthreads();

        // ---------- conv GEMM: M=128 (both s-halves), K=768, 24 slices ----------
        f32x4 acc2[8][4];
        #pragma unroll
        for (int i = 0; i < 8; ++i)
            #pragma unroll
            for (int j = 0; j < 4; ++j)
                acc2[i][j] = (f32x4){0.f, 0.f, 0.f, 0.f};

        const char* cw_w = cwsl + (size_t)(w * 64 + l15) * 64 + l4 * 16;
        fp16x8 bq[4];
        #pragma unroll
        for (int t = 0; t < 4; ++t)
            bq[t] = *(const fp16x8*)(cw_w + t * 1024);

        for (int ks = 0; ks < 24; ++ks) {
            fp16x8 bnx[4];
            if (ks < 23) {
                #pragma unroll
                for (int t = 0; t < 4; ++t)
                    bnx[t] = *(const fp16x8*)(cw_w + (ks + 1) * 16384 + t * 1024);
            }
            const int base = (l15 + (ks >> 3)) * HSTRIDE + (ks & 7) * 64 + l4 * 16;
            const char* h0p = hb0 + base;
            const char* h1p = hb1 + base;
            fp16x8 af[8];
            #pragma unroll
            for (int mt = 0; mt < 4; ++mt) {
                af[mt]     = *(const fp16x8*)(h0p + mt * (16 * HSTRIDE));
                af[mt + 4] = *(const fp16x8*)(h1p + mt * (16 * HSTRIDE));
            }
            #pragma unroll
            for (int t = 0; t < 4; ++t)
                #pragma unroll
                for (int mt = 0; mt < 8; ++mt)
                    acc2[mt][t] = __builtin_amdgcn_mfma_f32_16x16x32_f16(
                        af[mt], bq[t], acc2[mt][t], 0, 0, 0);
            #pragma unroll
            for (int t = 0; t < 4; ++t) bq[t] = bnx[t];
        }

        // epilogue: silu(conv + cb) * v, reduce over o -> red
        float cbv[4], vv[4];
        #pragma unroll
        for (int t = 0; t < 4; ++t) {
            int col = w * 64 + t * 16 + l15;
            cbv[t] = cb[col];
            vv[t]  = wsf[(dir ? WOFF_VB : WOFF_VF) + col];
        }
        #pragma unroll
        for (int mt = 0; mt < 8; ++mt) {
            #pragma unroll
            for (int q = 0; q < 4; ++q) {
                float v0 = 0.f;
                #pragma unroll
                for (int t = 0; t < 4; ++t)
                    v0 += silu_f(acc2[mt][t][q] + cbv[t]) * vv[t];
                v0 += __shfl_xor(v0, 1);
                v0 += __shfl_xor(v0, 2);
                v0 += __shfl_xor(v0, 4);
                v0 += __shfl_xor(v0, 8);
                if (l15 == 0) {
                    int idx = (mt >> 2) * 64 + (mt & 3) * 16 + l4 * 4 + q;
                    atomicAdd(&red[idx], v0);
                }
            }
        }
    }

    __syncthreads();
    const float constv = wsf[WOFF_CONST];
    if (tid < 62)
        out[(bn * 64 + s0) * 62 + tid] = red[tid] + constv;
    if (tid >= 64 && tid < 126)
        out[(bn * 64 + s1) * 62 + (tid - 64)] = red[tid] + constv;
}

extern "C" void kernel_launch(void* const* d_in, const int* in_sizes, int n_in,
                              void* d_out, int out_size, void* d_ws, size_t ws_size,
                              hipStream_t stream) {
    (void)in_sizes; (void)n_in; (void)out_size; (void)ws_size;
    const float* x    = (const float*)d_in[0];
    const float* corr = (const float*)d_in[1];
    const float* W1f  = (const float*)d_in[2];
    const float* b1f  = (const float*)d_in[3];
    const float* Cwf  = (const float*)d_in[4];
    const float* Cbf  = (const float*)d_in[5];
    const float* W2f  = (const float*)d_in[6];
    const float* b2f  = (const float*)d_in[7];
    const float* W1b  = (const float*)d_in[8];
    const float* b1b  = (const float*)d_in[9];
    const float* Cwb  = (const float*)d_in[10];
    const float* Cbb  = (const float*)d_in[11];
    const float* W2b  = (const float*)d_in[12];
    const float* b2b  = (const float*)d_in[13];
    const float* Wr   = (const float*)d_in[14];
    const float* br   = (const float*)d_in[15];
    float* out = (float*)d_out;
    float* wsf = (float*)d_ws;

    norm_kernel<<<512, 256, 0, stream>>>(corr, wsf);
    rowcount_kernel<<<512, 256, 0, stream>>>(wsf);
    pack_kernel<<<64, 256, 0, stream>>>(W2f, b2f, W2b, b2b, Wr, br,
                                        W1f, W1b, Cwf, Cwb, wsf);
    fused_main<<<1024, 256, 0, stream>>>(x, b1f, Cbf, b1b, Cbb, wsf, out);
}